// Round 4
// baseline (427.565 us; speedup 1.0000x reference)
//
#include <hip/hip_runtime.h>

#define BN_EPS 1e-5f
#define CHUNK 4096
#define MAXB 512  // max buckets (N up to 131072 with 256 nodes/bucket)

typedef __attribute__((ext_vector_type(8))) short short8v;  // 8 bf16 = 4 VGPRs
typedef __attribute__((ext_vector_type(4))) float f32x4;

// bf16 helpers (RNE pack, cheap unpack)
__device__ __forceinline__ unsigned short f2bf(float f) {
    unsigned int u = __float_as_uint(f);
    u += 0x7FFF + ((u >> 16) & 1);
    return (unsigned short)(u >> 16);
}
__device__ __forceinline__ float bf2f(unsigned short h) {
    return __uint_as_float((unsigned int)h << 16);
}
__device__ __forceinline__ float bflo(unsigned int u) { return __uint_as_float(u << 16); }
__device__ __forceinline__ float bfhi(unsigned int u) { return __uint_as_float(u & 0xffff0000u); }

__device__ __forceinline__ short8v pack8(const float* f) {
    short8v r;
#pragma unroll
    for (int i = 0; i < 8; i++) r[i] = (short)f2bf(f[i]);
    return r;
}

// ---------------- CSR build: bucketed, no global random scatter ----------------

__global__ __launch_bounds__(256) void bin_count(const int* __restrict__ ei, int E,
                                                 int* __restrict__ bcnt, int nbuck) {
    __shared__ int h[MAXB];
    for (int i = threadIdx.x; i < nbuck; i += 256) h[i] = 0;
    __syncthreads();
    int i = blockIdx.x * 256 + threadIdx.x, stride = gridDim.x * 256;
    for (int e = i; e < E; e += stride) {
        int d = ei[E + e];
        atomicAdd(&h[d >> 8], 1);
    }
    __syncthreads();
    for (int b = threadIdx.x; b < nbuck; b += 256)
        if (h[b]) atomicAdd(&bcnt[b], h[b]);
}

__global__ __launch_bounds__(512) void scan_small(const int* __restrict__ bcnt,
                                                  int* __restrict__ boff,
                                                  int* __restrict__ bpos,
                                                  int* __restrict__ row_ptr_end,
                                                  int nbuck, int E) {
    __shared__ int wsum[8];
    int tid = threadIdx.x, lane = tid & 63, wv = tid >> 6;
    int val = (tid < nbuck) ? bcnt[tid] : 0;
    int s = val;
#pragma unroll
    for (int off = 1; off < 64; off <<= 1) {
        int t = __shfl_up(s, off, 64);
        if (lane >= off) s += t;
    }
    if (lane == 63) wsum[wv] = s;
    __syncthreads();
    if (wv == 0) {
        int t = (lane < 8) ? wsum[lane] : 0;
#pragma unroll
        for (int off = 1; off < 8; off <<= 1) {
            int u = __shfl_up(t, off, 64);
            if (lane >= off) t += u;
        }
        if (lane < 8) wsum[lane] = t;
    }
    __syncthreads();
    int excl = ((wv == 0) ? 0 : wsum[wv - 1]) + s - val;
    if (tid < nbuck) { boff[tid] = excl; bpos[tid] = excl; }
    if (tid == 0) { boff[nbuck] = E; *row_ptr_end = E; }
}

__global__ __launch_bounds__(256) void bin_scatter(const int* __restrict__ ei, int E,
                                                   int* __restrict__ bpos,
                                                   int* __restrict__ binned, int nbuck) {
    __shared__ int h[MAXB];
    __shared__ int res[MAXB];
    int base = blockIdx.x * CHUNK;
    int cnt = min(CHUNK, E - base);
    int tid = threadIdx.x;
    for (int b = tid; b < nbuck; b += 256) h[b] = 0;
    __syncthreads();
    for (int k = tid; k < cnt; k += 256) {
        int d = ei[E + base + k];
        atomicAdd(&h[d >> 8], 1);
    }
    __syncthreads();
    for (int b = tid; b < nbuck; b += 256) {
        int c = h[b];
        res[b] = c ? atomicAdd(&bpos[b], c) : 0;
        h[b] = 0;  // reuse as rank counter
    }
    __syncthreads();
    for (int k = tid; k < cnt; k += 256) {
        int srcv = ei[base + k];
        int d = ei[E + base + k];
        int b = d >> 8;
        int r = atomicAdd(&h[b], 1);
        binned[res[b] + r] = ((d & 255) << 17) | srcv;  // src < 2^17
    }
}

__global__ __launch_bounds__(256) void bucket_csr(const int* __restrict__ binned,
                                                  const int* __restrict__ boff,
                                                  int* __restrict__ row_ptr,
                                                  int* __restrict__ esrc, int N) {
    __shared__ int ncnt[256];
    __shared__ int npos[256];
    __shared__ int wsum[4];
    int b = blockIdx.x, tid = threadIdx.x, lane = tid & 63, wv = tid >> 6;
    int lo = boff[b], hi = boff[b + 1];
    int base_node = b << 8;
    ncnt[tid] = 0;
    __syncthreads();
    for (int i = lo + tid; i < hi; i += 256)
        atomicAdd(&ncnt[binned[i] >> 17], 1);
    __syncthreads();
    int c = ncnt[tid];
    int s = c;
#pragma unroll
    for (int off = 1; off < 64; off <<= 1) {
        int t = __shfl_up(s, off, 64);
        if (lane >= off) s += t;
    }
    if (lane == 63) wsum[wv] = s;
    __syncthreads();
    int woff = 0;
#pragma unroll
    for (int i = 0; i < 4; i++) woff += (i < wv) ? wsum[i] : 0;
    int abspos = lo + woff + (s - c);
    if (base_node + tid < N) row_ptr[base_node + tid] = abspos;
    npos[tid] = abspos;
    __syncthreads();
    for (int i = lo + tid; i < hi; i += 256) {
        int val = binned[i];
        int r = atomicAdd(&npos[val >> 17], 1);
        esrc[r] = val & 0x1FFFF;
    }
}

// ---------------- MFMA dense kernels ----------------
// Layout facts (gfx950 mfma_f32_16x16x32_bf16):
//   A frag: lane holds A[lane&15][(lane>>4)*8 + j], j=0..7 (short8v)
//   B frag: lane holds B[(lane>>4)*8 + j][lane&15]
//   D frag: lane&15 = col, row = (lane>>4)*4 + reg
// Gather-feeding outputs are stored PLANE-MAJOR [8][N][8] bf16 (plane = col>>3)
// so each XCD's gather plane (1.6 MB) fits its private 4 MiB L2.

// Yp[8][N][8](bf16) = X[n][128](f32) @ W[64][128]^T   (no bias; added in gather)
__global__ __launch_bounds__(256) void linear_mfma(const float* __restrict__ X,
                                                   const float* __restrict__ W,
                                                   unsigned short* __restrict__ Y, int N) {
    __shared__ short8v al[16 * 16];  // 16 rows x 16 slots (K=128)
    int tid = threadIdx.x, wv = tid >> 6, lane = tid & 63;
    int lr = lane & 15, lh = lane >> 4;
    short8v bw[4];
    {
        const float* wrow = W + (size_t)(wv * 16 + lr) * 128;
#pragma unroll
        for (int kk = 0; kk < 4; kk++) {
            float tmp[8];
            *(float4*)tmp = *(const float4*)(wrow + kk * 32 + lh * 8);
            *(float4*)(tmp + 4) = *(const float4*)(wrow + kk * 32 + lh * 8 + 4);
            bw[kk] = pack8(tmp);
        }
    }
    int col = wv * 16 + lr;
    unsigned short* yb = Y + (size_t)(col >> 3) * N * 8 + (col & 7);
    int r = tid >> 4, s = tid & 15;  // staging: thread -> (row, slot)
    for (int nb = blockIdx.x * 16; nb < N; nb += gridDim.x * 16) {
        const float* xg = X + (size_t)(nb + r) * 128 + s * 8;
        float tmp[8];
        *(float4*)tmp = *(const float4*)xg;
        *(float4*)(tmp + 4) = *(const float4*)(xg + 4);
        al[r * 16 + (s ^ r)] = pack8(tmp);
        __syncthreads();
        f32x4 acc = {0.f, 0.f, 0.f, 0.f};
#pragma unroll
        for (int kk = 0; kk < 4; kk++) {
            short8v a = al[lr * 16 + ((kk * 4 + lh) ^ lr)];
            acc = __builtin_amdgcn_mfma_f32_16x16x32_bf16(a, bw[kk], acc, 0, 0, 0);
        }
#pragma unroll
        for (int ri = 0; ri < 4; ri++)
            yb[(size_t)(nb + lh * 4 + ri) * 8] = f2bf(acc[ri]);
        __syncthreads();
    }
}

// H(bf16, row-major) = relu(bn(T@W^T + b))   (T bf16 row-major, K=64)
__global__ __launch_bounds__(256) void mlp1_mfma(const unsigned short* __restrict__ T,
        const float* __restrict__ W, const float* __restrict__ b,
        const float* __restrict__ g, const float* __restrict__ be,
        const float* __restrict__ m, const float* __restrict__ v,
        unsigned short* __restrict__ H, int N) {
    __shared__ short8v al[16 * 8];  // 16 rows x 8 slots (K=64)
    int tid = threadIdx.x, wv = tid >> 6, lane = tid & 63;
    int lr = lane & 15, lh = lane >> 4;
    short8v bw[2];
    {
        const float* wrow = W + (size_t)(wv * 16 + lr) * 64;
#pragma unroll
        for (int kk = 0; kk < 2; kk++) {
            float tmp[8];
            *(float4*)tmp = *(const float4*)(wrow + kk * 32 + lh * 8);
            *(float4*)(tmp + 4) = *(const float4*)(wrow + kk * 32 + lh * 8 + 4);
            bw[kk] = pack8(tmp);
        }
    }
    int col = wv * 16 + lr;
    float bias = b[col];
    float sc = g[col] * rsqrtf(v[col] + BN_EPS);
    float cc = be[col] - m[col] * sc;
    int rr = tid >> 3, ss = tid & 7;  // staging: threads 0..127
    for (int nb = blockIdx.x * 16; nb < N; nb += gridDim.x * 16) {
        if (tid < 128) {
            const short8v* tg = (const short8v*)(T + (size_t)(nb + rr) * 64);
            al[rr * 8 + (ss ^ (rr & 7))] = tg[ss];
        }
        __syncthreads();
        f32x4 acc = {0.f, 0.f, 0.f, 0.f};
#pragma unroll
        for (int kk = 0; kk < 2; kk++) {
            short8v a = al[lr * 8 + ((kk * 4 + lh) ^ (lr & 7))];
            acc = __builtin_amdgcn_mfma_f32_16x16x32_bf16(a, bw[kk], acc, 0, 0, 0);
        }
        unsigned short* hb = H + (size_t)nb * 64 + col;
#pragma unroll
        for (int ri = 0; ri < 4; ri++) {
            float o = fmaxf((acc[ri] + bias) * sc + cc, 0.f);
            hb[(size_t)(lh * 4 + ri) * 64] = f2bf(o);
        }
        __syncthreads();
    }
}

// Yp[8][N][8](bf16) = relu(bn(T@W1^T + b1)) @ W2^T   (T bf16 row-major, K=64)
__global__ __launch_bounds__(256) void mlp2_mfma(const unsigned short* __restrict__ T,
        const float* __restrict__ W1, const float* __restrict__ b1,
        const float* __restrict__ g, const float* __restrict__ be,
        const float* __restrict__ m, const float* __restrict__ v,
        const float* __restrict__ W2, unsigned short* __restrict__ Y, int N) {
    __shared__ short8v al[16 * 8];
    __shared__ short8v hl[16 * 8];
    int tid = threadIdx.x, wv = tid >> 6, lane = tid & 63;
    int lr = lane & 15, lh = lane >> 4;
    short8v bw1[2], bw2[2];
    {
        const float* w1r = W1 + (size_t)(wv * 16 + lr) * 64;
        const float* w2r = W2 + (size_t)(wv * 16 + lr) * 64;
#pragma unroll
        for (int kk = 0; kk < 2; kk++) {
            float tmp[8];
            *(float4*)tmp = *(const float4*)(w1r + kk * 32 + lh * 8);
            *(float4*)(tmp + 4) = *(const float4*)(w1r + kk * 32 + lh * 8 + 4);
            bw1[kk] = pack8(tmp);
            *(float4*)tmp = *(const float4*)(w2r + kk * 32 + lh * 8);
            *(float4*)(tmp + 4) = *(const float4*)(w2r + kk * 32 + lh * 8 + 4);
            bw2[kk] = pack8(tmp);
        }
    }
    int col = wv * 16 + lr;
    float bias = b1[col];
    float sc = g[col] * rsqrtf(v[col] + BN_EPS);
    float cc = be[col] - m[col] * sc;
    unsigned short* hu = (unsigned short*)hl;
    unsigned short* yb = Y + (size_t)(col >> 3) * N * 8 + (col & 7);
    int rr = tid >> 3, ss = tid & 7;
    for (int nb = blockIdx.x * 16; nb < N; nb += gridDim.x * 16) {
        if (tid < 128) {
            const short8v* tg = (const short8v*)(T + (size_t)(nb + rr) * 64);
            al[rr * 8 + (ss ^ (rr & 7))] = tg[ss];
        }
        __syncthreads();
        f32x4 acc = {0.f, 0.f, 0.f, 0.f};
#pragma unroll
        for (int kk = 0; kk < 2; kk++) {
            short8v a = al[lr * 8 + ((kk * 4 + lh) ^ (lr & 7))];
            acc = __builtin_amdgcn_mfma_f32_16x16x32_bf16(a, bw1[kk], acc, 0, 0, 0);
        }
        // relu(bn(.)) -> hl (swizzled [16][64] bf16)
#pragma unroll
        for (int ri = 0; ri < 4; ri++) {
            float o = fmaxf((acc[ri] + bias) * sc + cc, 0.f);
            int row = lh * 4 + ri;
            int slot = (col >> 3) ^ (row & 7);
            hu[(row * 8 + slot) * 8 + (col & 7)] = f2bf(o);
        }
        __syncthreads();
        f32x4 acc2 = {0.f, 0.f, 0.f, 0.f};
#pragma unroll
        for (int kk = 0; kk < 2; kk++) {
            short8v a = hl[lr * 8 + ((kk * 4 + lh) ^ (lr & 7))];
            acc2 = __builtin_amdgcn_mfma_f32_16x16x32_bf16(a, bw2[kk], acc2, 0, 0, 0);
        }
#pragma unroll
        for (int ri = 0; ri < 4; ri++)
            yb[(size_t)(nb + lh * 4 + ri) * 8] = f2bf(acc2[ri]);
        __syncthreads();
    }
}

// ---------------- gather (plane-split): T[i](row-major bf16) = relu(Y[i] + bias + sum Y[src]) ----
// Yp is plane-major [8][N][8] bf16. Block b -> plane (b&7), node group (b>>3)*16.
// blockIdx round-robins XCDs => plane p stays on one XCD; 1.6 MB plane fits 4 MiB L2.
// Wave: 4 nodes; 2x16-edge batches issued fully parallel (clamped+masked); rare remainder.
__global__ __launch_bounds__(256) void gather_plane(const unsigned short* __restrict__ Yp,
        const int* __restrict__ row_ptr, const int* __restrict__ esrc,
        const float* __restrict__ bias, unsigned short* __restrict__ T, int N) {
    int b = blockIdx.x;
    int p = b & 7;            // plane == XCD (heuristic; correctness independent)
    int g = b >> 3;
    int wv = threadIdx.x >> 6, lane = threadIdx.x & 63;
    int grp = lane >> 2, fl = lane & 3;  // 16 edge slots x 4B (2 feats)
    const unsigned int* Y32 = (const unsigned int*)Yp + (size_t)p * N * 4;
    float bw0 = bias[p * 8 + fl * 2 + 0];
    float bw1 = bias[p * 8 + fl * 2 + 1];
    int nb0 = g * 16 + wv * 4;
    if (nb0 >= N) return;
    int e0[4], e1[4];
#pragma unroll
    for (int nn = 0; nn < 4; nn++) {
        int node = min(nb0 + nn, N - 1);
        e0[nn] = row_ptr[node];
        e1[nn] = row_ptr[node + 1];
    }
    int sA[4], sB[4];
#pragma unroll
    for (int nn = 0; nn < 4; nn++) {
        int la = max(e1[nn] - 1, 0);
        sA[nn] = esrc[min(e0[nn] + grp, la)];
        sB[nn] = esrc[min(e0[nn] + 16 + grp, la)];
    }
    unsigned int uS[4], uA[4], uB[4];
#pragma unroll
    for (int nn = 0; nn < 4; nn++) uS[nn] = Y32[(size_t)min(nb0 + nn, N - 1) * 4 + fl];
#pragma unroll
    for (int nn = 0; nn < 4; nn++) uA[nn] = Y32[(size_t)sA[nn] * 4 + fl];
#pragma unroll
    for (int nn = 0; nn < 4; nn++) uB[nn] = Y32[(size_t)sB[nn] * 4 + fl];
    float a0[4], a1[4];
#pragma unroll
    for (int nn = 0; nn < 4; nn++) {
        bool okA = e0[nn] + grp < e1[nn];
        bool okB = e0[nn] + 16 + grp < e1[nn];
        a0[nn] = (okA ? bflo(uA[nn]) : 0.f) + (okB ? bflo(uB[nn]) : 0.f);
        a1[nn] = (okA ? bfhi(uA[nn]) : 0.f) + (okB ? bfhi(uB[nn]) : 0.f);
        if (grp == 0) { a0[nn] += bflo(uS[nn]) + bw0; a1[nn] += bfhi(uS[nn]) + bw1; }
    }
    // remainder for deg > 32 (Poisson-16: ~0.02% of nodes)
#pragma unroll
    for (int nn = 0; nn < 4; nn++) {
        for (int e = e0[nn] + 32; e < e1[nn]; e += 16) {
            int ie = e + grp;
            int s = esrc[min(ie, e1[nn] - 1)];
            unsigned int u = Y32[(size_t)s * 4 + fl];
            bool ok = ie < e1[nn];
            a0[nn] += ok ? bflo(u) : 0.f;
            a1[nn] += ok ? bfhi(u) : 0.f;
        }
    }
#pragma unroll
    for (int nn = 0; nn < 4; nn++) {
#pragma unroll
        for (int off = 4; off <= 32; off <<= 1) {
            a0[nn] += __shfl_xor(a0[nn], off, 64);
            a1[nn] += __shfl_xor(a1[nn], off, 64);
        }
    }
    if (grp == 0) {
#pragma unroll
        for (int nn = 0; nn < 4; nn++) {
            int node = nb0 + nn;
            if (node < N) {
                unsigned int o = (unsigned int)f2bf(fmaxf(a0[nn], 0.f))
                               | ((unsigned int)f2bf(fmaxf(a1[nn], 0.f)) << 16);
                ((unsigned int*)T)[(size_t)node * 32 + p * 4 + fl] = o;
            }
        }
    }
}

// ---------------- mean pool per graph (batch is sorted) ----------------
__global__ __launch_bounds__(256) void pool_kernel(const unsigned short* __restrict__ H,
                                                   const int* __restrict__ batch,
                                                   float* __restrict__ out, int N) {
    __shared__ float part[4][64];
    int g = blockIdx.x;
    int tid = threadIdx.x, wv = tid >> 6, lane = tid & 63;
    int lo = 0, hi = N;
    while (lo < hi) { int mid = (lo + hi) >> 1; if (batch[mid] < g) lo = mid + 1; else hi = mid; }
    int start = lo;
    hi = N;
    while (lo < hi) { int mid = (lo + hi) >> 1; if (batch[mid] < g + 1) lo = mid + 1; else hi = mid; }
    int end = lo;
    float acc = 0.f;
    for (int i = start + wv; i < end; i += 4) acc += bf2f(H[(size_t)i * 64 + lane]);
    part[wv][lane] = acc;
    __syncthreads();
    if (tid < 64) {
        float sfin = part[0][tid] + part[1][tid] + part[2][tid] + part[3][tid];
        float cnt = (float)(end - start);
        out[(size_t)g * 64 + tid] = sfin / fmaxf(cnt, 1.f);
    }
}

extern "C" void kernel_launch(void* const* d_in, const int* in_sizes, int n_in,
                              void* d_out, int out_size, void* d_ws, size_t ws_size,
                              hipStream_t stream) {
    const float* x   = (const float*)d_in[0];
    const int*   ei  = (const int*)d_in[1];
    const int*   bat = (const int*)d_in[2];
    const float* W1a = (const float*)d_in[3];
    const float* b1a = (const float*)d_in[4];
    const float* W1b = (const float*)d_in[5];
    const float* b1b = (const float*)d_in[6];
    const float* g1  = (const float*)d_in[7];
    const float* be1 = (const float*)d_in[8];
    const float* m1  = (const float*)d_in[9];
    const float* v1  = (const float*)d_in[10];
    const float* W2a = (const float*)d_in[11];
    const float* b2a = (const float*)d_in[12];
    const float* W2b = (const float*)d_in[13];
    const float* b2b = (const float*)d_in[14];
    const float* g2  = (const float*)d_in[15];
    const float* be2 = (const float*)d_in[16];
    const float* m2  = (const float*)d_in[17];
    const float* v2  = (const float*)d_in[18];
    float* out = (float*)d_out;

    int N = in_sizes[0] / 128;
    int E = in_sizes[1] / 2;
    int G = out_size / 64;
    int nbuck = (N + 255) >> 8;

    // workspace layout (bf16 feature buffers)
    char* ws = (char*)d_ws;
    int* row_ptr = (int*)ws;                              // N+1 (padded)
    int* bcnt = row_ptr + ((N + 1 + 3) & ~3);             // MAXB
    int* boff = bcnt + MAXB;                              // MAXB+1
    int* bpos = boff + MAXB + 4;                          // MAXB
    int* esrc = bpos + MAXB;                              // E
    unsigned short* bufA = (unsigned short*)(esrc + E);   // N*64 bf16
    unsigned short* bufB = bufA + (size_t)N * 64;         // N*64 bf16
    int* binned = (int*)bufB;                             // aliases bufB (dead until gather#1)

    // CSR build
    hipMemsetAsync(bcnt, 0, MAXB * sizeof(int), stream);
    bin_count<<<512, 256, 0, stream>>>(ei, E, bcnt, nbuck);
    scan_small<<<1, 512, 0, stream>>>(bcnt, boff, bpos, row_ptr + N, nbuck, E);
    bin_scatter<<<(E + CHUNK - 1) / CHUNK, 256, 0, stream>>>(ei, E, bpos, binned, nbuck);
    bucket_csr<<<nbuck, 256, 0, stream>>>(binned, boff, row_ptr, esrc, N);

    int ngrp = (N + 15) / 16;

    // layer 1
    linear_mfma<<<2048, 256, 0, stream>>>(x, W1a, bufA, N);
    gather_plane<<<8 * ngrp, 256, 0, stream>>>(bufA, row_ptr, esrc, b1a, bufB, N);
    mlp2_mfma<<<2048, 256, 0, stream>>>(bufB, W1b, b1b, g1, be1, m1, v1, W2a, bufA, N);

    // layer 2
    gather_plane<<<8 * ngrp, 256, 0, stream>>>(bufA, row_ptr, esrc, b2a, bufB, N);
    mlp1_mfma<<<2048, 256, 0, stream>>>(bufB, W2b, b2b, g2, be2, m2, v2, bufA, N);

    // mean pool
    pool_kernel<<<G, 256, 0, stream>>>(bufA, bat, out, N);
}

// Round 5
// 381.242 us; speedup vs baseline: 1.1215x; 1.1215x over previous
//
#include <hip/hip_runtime.h>

#define BN_EPS 1e-5f
#define CHUNK 4096
#define MAXB 512  // max buckets (N up to 131072 with 256 nodes/bucket)

typedef __attribute__((ext_vector_type(8))) short short8v;  // 8 bf16 = 4 VGPRs
typedef __attribute__((ext_vector_type(4))) float f32x4;

// bf16 helpers (RNE pack, cheap unpack)
__device__ __forceinline__ unsigned short f2bf(float f) {
    unsigned int u = __float_as_uint(f);
    u += 0x7FFF + ((u >> 16) & 1);
    return (unsigned short)(u >> 16);
}
__device__ __forceinline__ float bf2f(unsigned short h) {
    return __uint_as_float((unsigned int)h << 16);
}
__device__ __forceinline__ float bflo(unsigned int u) { return __uint_as_float(u << 16); }
__device__ __forceinline__ float bfhi(unsigned int u) { return __uint_as_float(u & 0xffff0000u); }

__device__ __forceinline__ short8v pack8(const float* f) {
    short8v r;
#pragma unroll
    for (int i = 0; i < 8; i++) r[i] = (short)f2bf(f[i]);
    return r;
}

// ---------------- CSR build: bucketed, no global random scatter ----------------

__global__ __launch_bounds__(256) void bin_count(const int* __restrict__ ei, int E,
                                                 int* __restrict__ bcnt, int nbuck) {
    __shared__ int h[MAXB];
    for (int i = threadIdx.x; i < nbuck; i += 256) h[i] = 0;
    __syncthreads();
    int i = blockIdx.x * 256 + threadIdx.x, stride = gridDim.x * 256;
    for (int e = i; e < E; e += stride) {
        int d = ei[E + e];
        atomicAdd(&h[d >> 8], 1);
    }
    __syncthreads();
    for (int b = threadIdx.x; b < nbuck; b += 256)
        if (h[b]) atomicAdd(&bcnt[b], h[b]);
}

__global__ __launch_bounds__(512) void scan_small(const int* __restrict__ bcnt,
                                                  int* __restrict__ boff,
                                                  int* __restrict__ bpos,
                                                  int* __restrict__ row_ptr_end,
                                                  int nbuck, int E) {
    __shared__ int wsum[8];
    int tid = threadIdx.x, lane = tid & 63, wv = tid >> 6;
    int val = (tid < nbuck) ? bcnt[tid] : 0;
    int s = val;
#pragma unroll
    for (int off = 1; off < 64; off <<= 1) {
        int t = __shfl_up(s, off, 64);
        if (lane >= off) s += t;
    }
    if (lane == 63) wsum[wv] = s;
    __syncthreads();
    if (wv == 0) {
        int t = (lane < 8) ? wsum[lane] : 0;
#pragma unroll
        for (int off = 1; off < 8; off <<= 1) {
            int u = __shfl_up(t, off, 64);
            if (lane >= off) t += u;
        }
        if (lane < 8) wsum[lane] = t;
    }
    __syncthreads();
    int excl = ((wv == 0) ? 0 : wsum[wv - 1]) + s - val;
    if (tid < nbuck) { boff[tid] = excl; bpos[tid] = excl; }
    if (tid == 0) { boff[nbuck] = E; *row_ptr_end = E; }
}

__global__ __launch_bounds__(256) void bin_scatter(const int* __restrict__ ei, int E,
                                                   int* __restrict__ bpos,
                                                   int* __restrict__ binned, int nbuck) {
    __shared__ int h[MAXB];
    __shared__ int res[MAXB];
    int base = blockIdx.x * CHUNK;
    int cnt = min(CHUNK, E - base);
    int tid = threadIdx.x;
    for (int b = tid; b < nbuck; b += 256) h[b] = 0;
    __syncthreads();
    for (int k = tid; k < cnt; k += 256) {
        int d = ei[E + base + k];
        atomicAdd(&h[d >> 8], 1);
    }
    __syncthreads();
    for (int b = tid; b < nbuck; b += 256) {
        int c = h[b];
        res[b] = c ? atomicAdd(&bpos[b], c) : 0;
        h[b] = 0;  // reuse as rank counter
    }
    __syncthreads();
    for (int k = tid; k < cnt; k += 256) {
        int srcv = ei[base + k];
        int d = ei[E + base + k];
        int b = d >> 8;
        int r = atomicAdd(&h[b], 1);
        binned[res[b] + r] = ((d & 255) << 17) | srcv;  // src < 2^17
    }
}

__global__ __launch_bounds__(256) void bucket_csr(const int* __restrict__ binned,
                                                  const int* __restrict__ boff,
                                                  int* __restrict__ row_ptr,
                                                  int* __restrict__ esrc, int N) {
    __shared__ int ncnt[256];
    __shared__ int npos[256];
    __shared__ int wsum[4];
    int b = blockIdx.x, tid = threadIdx.x, lane = tid & 63, wv = tid >> 6;
    int lo = boff[b], hi = boff[b + 1];
    int base_node = b << 8;
    ncnt[tid] = 0;
    __syncthreads();
    for (int i = lo + tid; i < hi; i += 256)
        atomicAdd(&ncnt[binned[i] >> 17], 1);
    __syncthreads();
    int c = ncnt[tid];
    int s = c;
#pragma unroll
    for (int off = 1; off < 64; off <<= 1) {
        int t = __shfl_up(s, off, 64);
        if (lane >= off) s += t;
    }
    if (lane == 63) wsum[wv] = s;
    __syncthreads();
    int woff = 0;
#pragma unroll
    for (int i = 0; i < 4; i++) woff += (i < wv) ? wsum[i] : 0;
    int abspos = lo + woff + (s - c);
    if (base_node + tid < N) row_ptr[base_node + tid] = abspos;
    npos[tid] = abspos;
    __syncthreads();
    for (int i = lo + tid; i < hi; i += 256) {
        int val = binned[i];
        int r = atomicAdd(&npos[val >> 17], 1);
        esrc[r] = val & 0x1FFFF;
    }
}

// ---------------- MFMA dense kernels ----------------
// Layout facts (gfx950 mfma_f32_16x16x32_bf16):
//   A frag: lane holds A[lane&15][(lane>>4)*8 + j], j=0..7 (short8v)
//   B frag: lane holds B[(lane>>4)*8 + j][lane&15]
//   D frag: lane&15 = col, row = (lane>>4)*4 + reg
// Gather-feeding outputs are stored PLANE-MAJOR [8][N][8] bf16 (plane = col>>3)
// so each XCD's gather plane (1.6 MB) fits its private 4 MiB L2.

// Yp[8][N][8](bf16) = X[n][128](f32) @ W[64][128]^T   (no bias; added in gather)
__global__ __launch_bounds__(256) void linear_mfma(const float* __restrict__ X,
                                                   const float* __restrict__ W,
                                                   unsigned short* __restrict__ Y, int N) {
    __shared__ short8v al[16 * 16];  // 16 rows x 16 slots (K=128)
    int tid = threadIdx.x, wv = tid >> 6, lane = tid & 63;
    int lr = lane & 15, lh = lane >> 4;
    short8v bw[4];
    {
        const float* wrow = W + (size_t)(wv * 16 + lr) * 128;
#pragma unroll
        for (int kk = 0; kk < 4; kk++) {
            float tmp[8];
            *(float4*)tmp = *(const float4*)(wrow + kk * 32 + lh * 8);
            *(float4*)(tmp + 4) = *(const float4*)(wrow + kk * 32 + lh * 8 + 4);
            bw[kk] = pack8(tmp);
        }
    }
    int col = wv * 16 + lr;
    unsigned short* yb = Y + (size_t)(col >> 3) * N * 8 + (col & 7);
    int r = tid >> 4, s = tid & 15;  // staging: thread -> (row, slot)
    for (int nb = blockIdx.x * 16; nb < N; nb += gridDim.x * 16) {
        const float* xg = X + (size_t)(nb + r) * 128 + s * 8;
        float tmp[8];
        *(float4*)tmp = *(const float4*)xg;
        *(float4*)(tmp + 4) = *(const float4*)(xg + 4);
        al[r * 16 + (s ^ r)] = pack8(tmp);
        __syncthreads();
        f32x4 acc = {0.f, 0.f, 0.f, 0.f};
#pragma unroll
        for (int kk = 0; kk < 4; kk++) {
            short8v a = al[lr * 16 + ((kk * 4 + lh) ^ lr)];
            acc = __builtin_amdgcn_mfma_f32_16x16x32_bf16(a, bw[kk], acc, 0, 0, 0);
        }
#pragma unroll
        for (int ri = 0; ri < 4; ri++)
            yb[(size_t)(nb + lh * 4 + ri) * 8] = f2bf(acc[ri]);
        __syncthreads();
    }
}

// H(bf16, row-major) = relu(bn(T@W^T + b))   (T bf16 row-major, K=64)
__global__ __launch_bounds__(256) void mlp1_mfma(const unsigned short* __restrict__ T,
        const float* __restrict__ W, const float* __restrict__ b,
        const float* __restrict__ g, const float* __restrict__ be,
        const float* __restrict__ m, const float* __restrict__ v,
        unsigned short* __restrict__ H, int N) {
    __shared__ short8v al[16 * 8];  // 16 rows x 8 slots (K=64)
    int tid = threadIdx.x, wv = tid >> 6, lane = tid & 63;
    int lr = lane & 15, lh = lane >> 4;
    short8v bw[2];
    {
        const float* wrow = W + (size_t)(wv * 16 + lr) * 64;
#pragma unroll
        for (int kk = 0; kk < 2; kk++) {
            float tmp[8];
            *(float4*)tmp = *(const float4*)(wrow + kk * 32 + lh * 8);
            *(float4*)(tmp + 4) = *(const float4*)(wrow + kk * 32 + lh * 8 + 4);
            bw[kk] = pack8(tmp);
        }
    }
    int col = wv * 16 + lr;
    float bias = b[col];
    float sc = g[col] * rsqrtf(v[col] + BN_EPS);
    float cc = be[col] - m[col] * sc;
    int rr = tid >> 3, ss = tid & 7;  // staging: threads 0..127
    for (int nb = blockIdx.x * 16; nb < N; nb += gridDim.x * 16) {
        if (tid < 128) {
            const short8v* tg = (const short8v*)(T + (size_t)(nb + rr) * 64);
            al[rr * 8 + (ss ^ (rr & 7))] = tg[ss];
        }
        __syncthreads();
        f32x4 acc = {0.f, 0.f, 0.f, 0.f};
#pragma unroll
        for (int kk = 0; kk < 2; kk++) {
            short8v a = al[lr * 8 + ((kk * 4 + lh) ^ (lr & 7))];
            acc = __builtin_amdgcn_mfma_f32_16x16x32_bf16(a, bw[kk], acc, 0, 0, 0);
        }
        unsigned short* hb = H + (size_t)nb * 64 + col;
#pragma unroll
        for (int ri = 0; ri < 4; ri++) {
            float o = fmaxf((acc[ri] + bias) * sc + cc, 0.f);
            hb[(size_t)(lh * 4 + ri) * 64] = f2bf(o);
        }
        __syncthreads();
    }
}

// Yp[8][N][8](bf16) = relu(bn(T@W1^T + b1)) @ W2^T   (T bf16 row-major, K=64)
__global__ __launch_bounds__(256) void mlp2_mfma(const unsigned short* __restrict__ T,
        const float* __restrict__ W1, const float* __restrict__ b1,
        const float* __restrict__ g, const float* __restrict__ be,
        const float* __restrict__ m, const float* __restrict__ v,
        const float* __restrict__ W2, unsigned short* __restrict__ Y, int N) {
    __shared__ short8v al[16 * 8];
    __shared__ short8v hl[16 * 8];
    int tid = threadIdx.x, wv = tid >> 6, lane = tid & 63;
    int lr = lane & 15, lh = lane >> 4;
    short8v bw1[2], bw2[2];
    {
        const float* w1r = W1 + (size_t)(wv * 16 + lr) * 64;
        const float* w2r = W2 + (size_t)(wv * 16 + lr) * 64;
#pragma unroll
        for (int kk = 0; kk < 2; kk++) {
            float tmp[8];
            *(float4*)tmp = *(const float4*)(w1r + kk * 32 + lh * 8);
            *(float4*)(tmp + 4) = *(const float4*)(w1r + kk * 32 + lh * 8 + 4);
            bw1[kk] = pack8(tmp);
            *(float4*)tmp = *(const float4*)(w2r + kk * 32 + lh * 8);
            *(float4*)(tmp + 4) = *(const float4*)(w2r + kk * 32 + lh * 8 + 4);
            bw2[kk] = pack8(tmp);
        }
    }
    int col = wv * 16 + lr;
    float bias = b1[col];
    float sc = g[col] * rsqrtf(v[col] + BN_EPS);
    float cc = be[col] - m[col] * sc;
    unsigned short* hu = (unsigned short*)hl;
    unsigned short* yb = Y + (size_t)(col >> 3) * N * 8 + (col & 7);
    int rr = tid >> 3, ss = tid & 7;
    for (int nb = blockIdx.x * 16; nb < N; nb += gridDim.x * 16) {
        if (tid < 128) {
            const short8v* tg = (const short8v*)(T + (size_t)(nb + rr) * 64);
            al[rr * 8 + (ss ^ (rr & 7))] = tg[ss];
        }
        __syncthreads();
        f32x4 acc = {0.f, 0.f, 0.f, 0.f};
#pragma unroll
        for (int kk = 0; kk < 2; kk++) {
            short8v a = al[lr * 8 + ((kk * 4 + lh) ^ (lr & 7))];
            acc = __builtin_amdgcn_mfma_f32_16x16x32_bf16(a, bw1[kk], acc, 0, 0, 0);
        }
        // relu(bn(.)) -> hl (swizzled [16][64] bf16)
#pragma unroll
        for (int ri = 0; ri < 4; ri++) {
            float o = fmaxf((acc[ri] + bias) * sc + cc, 0.f);
            int row = lh * 4 + ri;
            int slot = (col >> 3) ^ (row & 7);
            hu[(row * 8 + slot) * 8 + (col & 7)] = f2bf(o);
        }
        __syncthreads();
        f32x4 acc2 = {0.f, 0.f, 0.f, 0.f};
#pragma unroll
        for (int kk = 0; kk < 2; kk++) {
            short8v a = hl[lr * 8 + ((kk * 4 + lh) ^ (lr & 7))];
            acc2 = __builtin_amdgcn_mfma_f32_16x16x32_bf16(a, bw2[kk], acc2, 0, 0, 0);
        }
#pragma unroll
        for (int ri = 0; ri < 4; ri++)
            yb[(size_t)(nb + lh * 4 + ri) * 8] = f2bf(acc2[ri]);
        __syncthreads();
    }
}

// ---------------- gather (plane-split v2) ----------------
// Yp plane-major [8][N][8] bf16: one uint4 load = full 8-feat row (16B).
// Block b -> plane (b&7) stays on one XCD (round-robin); plane (1.6MB) fits 4MiB L2.
// Wave = 16 nodes x 4 edge slots; per-lane strided loop, NO masks/clamps in body.
// One 2-level shfl_xor reduce per node; self+bias+relu+pack on slot-0 lanes.
__global__ __launch_bounds__(256) void gather_plane(const unsigned short* __restrict__ Yp,
        const int* __restrict__ row_ptr, const int* __restrict__ esrc,
        const float* __restrict__ bias, unsigned short* __restrict__ T, int N) {
    int b = blockIdx.x;
    int p = b & 7;
    int g = b >> 3;
    int wv = threadIdx.x >> 6, lane = threadIdx.x & 63;
    int nsub = lane >> 2, slot = lane & 3;
    int node = g * 64 + wv * 16 + nsub;
    bool valid = node < N;
    int nd = valid ? node : 0;
    int e0 = row_ptr[nd];
    int e1 = valid ? row_ptr[nd + 1] : e0;
    const uint4* Yrow = (const uint4*)(Yp + (size_t)p * N * 8);
    float a0 = 0.f, a1 = 0.f, a2 = 0.f, a3 = 0.f, a4 = 0.f, a5 = 0.f, a6 = 0.f, a7 = 0.f;
    for (int e = e0 + slot; e < e1; e += 4) {
        int s = esrc[e];
        uint4 q = Yrow[s];
        a0 += bflo(q.x); a1 += bfhi(q.x);
        a2 += bflo(q.y); a3 += bfhi(q.y);
        a4 += bflo(q.z); a5 += bfhi(q.z);
        a6 += bflo(q.w); a7 += bfhi(q.w);
    }
#pragma unroll
    for (int off = 1; off <= 2; off <<= 1) {
        a0 += __shfl_xor(a0, off, 64);
        a1 += __shfl_xor(a1, off, 64);
        a2 += __shfl_xor(a2, off, 64);
        a3 += __shfl_xor(a3, off, 64);
        a4 += __shfl_xor(a4, off, 64);
        a5 += __shfl_xor(a5, off, 64);
        a6 += __shfl_xor(a6, off, 64);
        a7 += __shfl_xor(a7, off, 64);
    }
    if (slot == 0 && valid) {
        uint4 qs = Yrow[node];
        float4 bl = *(const float4*)(bias + p * 8);
        float4 bh = *(const float4*)(bias + p * 8 + 4);
        a0 += bflo(qs.x) + bl.x; a1 += bfhi(qs.x) + bl.y;
        a2 += bflo(qs.y) + bl.z; a3 += bfhi(qs.y) + bl.w;
        a4 += bflo(qs.z) + bh.x; a5 += bfhi(qs.z) + bh.y;
        a6 += bflo(qs.w) + bh.z; a7 += bfhi(qs.w) + bh.w;
        uint4 o;
        o.x = (unsigned int)f2bf(fmaxf(a0, 0.f)) | ((unsigned int)f2bf(fmaxf(a1, 0.f)) << 16);
        o.y = (unsigned int)f2bf(fmaxf(a2, 0.f)) | ((unsigned int)f2bf(fmaxf(a3, 0.f)) << 16);
        o.z = (unsigned int)f2bf(fmaxf(a4, 0.f)) | ((unsigned int)f2bf(fmaxf(a5, 0.f)) << 16);
        o.w = (unsigned int)f2bf(fmaxf(a6, 0.f)) | ((unsigned int)f2bf(fmaxf(a7, 0.f)) << 16);
        *(uint4*)(T + (size_t)node * 64 + p * 8) = o;
    }
}

// ---------------- mean pool per graph (batch is sorted) ----------------
__global__ __launch_bounds__(256) void pool_kernel(const unsigned short* __restrict__ H,
                                                   const int* __restrict__ batch,
                                                   float* __restrict__ out, int N) {
    __shared__ float part[4][64];
    int g = blockIdx.x;
    int tid = threadIdx.x, wv = tid >> 6, lane = tid & 63;
    int lo = 0, hi = N;
    while (lo < hi) { int mid = (lo + hi) >> 1; if (batch[mid] < g) lo = mid + 1; else hi = mid; }
    int start = lo;
    hi = N;
    while (lo < hi) { int mid = (lo + hi) >> 1; if (batch[mid] < g + 1) lo = mid + 1; else hi = mid; }
    int end = lo;
    float acc = 0.f;
    for (int i = start + wv; i < end; i += 4) acc += bf2f(H[(size_t)i * 64 + lane]);
    part[wv][lane] = acc;
    __syncthreads();
    if (tid < 64) {
        float sfin = part[0][tid] + part[1][tid] + part[2][tid] + part[3][tid];
        float cnt = (float)(end - start);
        out[(size_t)g * 64 + tid] = sfin / fmaxf(cnt, 1.f);
    }
}

extern "C" void kernel_launch(void* const* d_in, const int* in_sizes, int n_in,
                              void* d_out, int out_size, void* d_ws, size_t ws_size,
                              hipStream_t stream) {
    const float* x   = (const float*)d_in[0];
    const int*   ei  = (const int*)d_in[1];
    const int*   bat = (const int*)d_in[2];
    const float* W1a = (const float*)d_in[3];
    const float* b1a = (const float*)d_in[4];
    const float* W1b = (const float*)d_in[5];
    const float* b1b = (const float*)d_in[6];
    const float* g1  = (const float*)d_in[7];
    const float* be1 = (const float*)d_in[8];
    const float* m1  = (const float*)d_in[9];
    const float* v1  = (const float*)d_in[10];
    const float* W2a = (const float*)d_in[11];
    const float* b2a = (const float*)d_in[12];
    const float* W2b = (const float*)d_in[13];
    const float* b2b = (const float*)d_in[14];
    const float* g2  = (const float*)d_in[15];
    const float* be2 = (const float*)d_in[16];
    const float* m2  = (const float*)d_in[17];
    const float* v2  = (const float*)d_in[18];
    float* out = (float*)d_out;

    int N = in_sizes[0] / 128;
    int E = in_sizes[1] / 2;
    int G = out_size / 64;
    int nbuck = (N + 255) >> 8;

    // workspace layout (bf16 feature buffers)
    char* ws = (char*)d_ws;
    int* row_ptr = (int*)ws;                              // N+1 (padded)
    int* bcnt = row_ptr + ((N + 1 + 3) & ~3);             // MAXB
    int* boff = bcnt + MAXB;                              // MAXB+1
    int* bpos = boff + MAXB + 4;                          // MAXB
    int* esrc = bpos + MAXB;                              // E
    unsigned short* bufA = (unsigned short*)(esrc + E);   // N*64 bf16 (16B aligned)
    unsigned short* bufB = bufA + (size_t)N * 64;         // N*64 bf16
    int* binned = (int*)bufB;                             // aliases bufB (dead until gather#1)

    // CSR build
    hipMemsetAsync(bcnt, 0, MAXB * sizeof(int), stream);
    bin_count<<<512, 256, 0, stream>>>(ei, E, bcnt, nbuck);
    scan_small<<<1, 512, 0, stream>>>(bcnt, boff, bpos, row_ptr + N, nbuck, E);
    bin_scatter<<<(E + CHUNK - 1) / CHUNK, 256, 0, stream>>>(ei, E, bpos, binned, nbuck);
    bucket_csr<<<nbuck, 256, 0, stream>>>(binned, boff, row_ptr, esrc, N);

    int ngb = (N + 63) / 64;

    // layer 1
    linear_mfma<<<2048, 256, 0, stream>>>(x, W1a, bufA, N);
    gather_plane<<<8 * ngb, 256, 0, stream>>>(bufA, row_ptr, esrc, b1a, bufB, N);
    mlp2_mfma<<<2048, 256, 0, stream>>>(bufB, W1b, b1b, g1, be1, m1, v1, W2a, bufA, N);

    // layer 2
    gather_plane<<<8 * ngb, 256, 0, stream>>>(bufA, row_ptr, esrc, b2a, bufB, N);
    mlp1_mfma<<<2048, 256, 0, stream>>>(bufB, W2b, b2b, g2, be2, m2, v2, bufA, N);

    // mean pool
    pool_kernel<<<G, 256, 0, stream>>>(bufA, bat, out, N);
}

// Round 6
// 373.137 us; speedup vs baseline: 1.1459x; 1.0217x over previous
//
#include <hip/hip_runtime.h>

#define BN_EPS 1e-5f
#define CHUNK 4096
#define MAXB 512  // max buckets (N up to 131072 with 256 nodes/bucket)

typedef __attribute__((ext_vector_type(8))) short short8v;  // 8 bf16 = 4 VGPRs
typedef __attribute__((ext_vector_type(4))) float f32x4;

// bf16 helpers (RNE pack, cheap unpack)
__device__ __forceinline__ unsigned short f2bf(float f) {
    unsigned int u = __float_as_uint(f);
    u += 0x7FFF + ((u >> 16) & 1);
    return (unsigned short)(u >> 16);
}
__device__ __forceinline__ float bf2f(unsigned short h) {
    return __uint_as_float((unsigned int)h << 16);
}
__device__ __forceinline__ float bflo(unsigned int u) { return __uint_as_float(u << 16); }
__device__ __forceinline__ float bfhi(unsigned int u) { return __uint_as_float(u & 0xffff0000u); }

__device__ __forceinline__ short8v pack8(const float* f) {
    short8v r;
#pragma unroll
    for (int i = 0; i < 8; i++) r[i] = (short)f2bf(f[i]);
    return r;
}

// ---------------- CSR build: bucketed, no global random scatter ----------------

__global__ __launch_bounds__(256) void bin_count(const int* __restrict__ ei, int E,
                                                 int* __restrict__ bcnt, int nbuck) {
    __shared__ int h[MAXB];
    for (int i = threadIdx.x; i < nbuck; i += 256) h[i] = 0;
    __syncthreads();
    int i = blockIdx.x * 256 + threadIdx.x, stride = gridDim.x * 256;
    for (int e = i; e < E; e += stride) {
        int d = ei[E + e];
        atomicAdd(&h[d >> 8], 1);
    }
    __syncthreads();
    for (int b = threadIdx.x; b < nbuck; b += 256)
        if (h[b]) atomicAdd(&bcnt[b], h[b]);
}

__global__ __launch_bounds__(512) void scan_small(const int* __restrict__ bcnt,
                                                  int* __restrict__ boff,
                                                  int* __restrict__ bpos,
                                                  int* __restrict__ row_ptr_end,
                                                  int nbuck, int E) {
    __shared__ int wsum[8];
    int tid = threadIdx.x, lane = tid & 63, wv = tid >> 6;
    int val = (tid < nbuck) ? bcnt[tid] : 0;
    int s = val;
#pragma unroll
    for (int off = 1; off < 64; off <<= 1) {
        int t = __shfl_up(s, off, 64);
        if (lane >= off) s += t;
    }
    if (lane == 63) wsum[wv] = s;
    __syncthreads();
    if (wv == 0) {
        int t = (lane < 8) ? wsum[lane] : 0;
#pragma unroll
        for (int off = 1; off < 8; off <<= 1) {
            int u = __shfl_up(t, off, 64);
            if (lane >= off) t += u;
        }
        if (lane < 8) wsum[lane] = t;
    }
    __syncthreads();
    int excl = ((wv == 0) ? 0 : wsum[wv - 1]) + s - val;
    if (tid < nbuck) { boff[tid] = excl; bpos[tid] = excl; }
    if (tid == 0) { boff[nbuck] = E; *row_ptr_end = E; }
}

__global__ __launch_bounds__(256) void bin_scatter(const int* __restrict__ ei, int E,
                                                   int* __restrict__ bpos,
                                                   int* __restrict__ binned, int nbuck) {
    __shared__ int h[MAXB];
    __shared__ int res[MAXB];
    int base = blockIdx.x * CHUNK;
    int cnt = min(CHUNK, E - base);
    int tid = threadIdx.x;
    for (int b = tid; b < nbuck; b += 256) h[b] = 0;
    __syncthreads();
    for (int k = tid; k < cnt; k += 256) {
        int d = ei[E + base + k];
        atomicAdd(&h[d >> 8], 1);
    }
    __syncthreads();
    for (int b = tid; b < nbuck; b += 256) {
        int c = h[b];
        res[b] = c ? atomicAdd(&bpos[b], c) : 0;
        h[b] = 0;  // reuse as rank counter
    }
    __syncthreads();
    for (int k = tid; k < cnt; k += 256) {
        int srcv = ei[base + k];
        int d = ei[E + base + k];
        int b = d >> 8;
        int r = atomicAdd(&h[b], 1);
        binned[res[b] + r] = ((d & 255) << 17) | srcv;  // src < 2^17
    }
}

__global__ __launch_bounds__(256) void bucket_csr(const int* __restrict__ binned,
                                                  const int* __restrict__ boff,
                                                  int* __restrict__ row_ptr,
                                                  int* __restrict__ esrc, int N) {
    __shared__ int ncnt[256];
    __shared__ int npos[256];
    __shared__ int wsum[4];
    int b = blockIdx.x, tid = threadIdx.x, lane = tid & 63, wv = tid >> 6;
    int lo = boff[b], hi = boff[b + 1];
    int base_node = b << 8;
    ncnt[tid] = 0;
    __syncthreads();
    for (int i = lo + tid; i < hi; i += 256)
        atomicAdd(&ncnt[binned[i] >> 17], 1);
    __syncthreads();
    int c = ncnt[tid];
    int s = c;
#pragma unroll
    for (int off = 1; off < 64; off <<= 1) {
        int t = __shfl_up(s, off, 64);
        if (lane >= off) s += t;
    }
    if (lane == 63) wsum[wv] = s;
    __syncthreads();
    int woff = 0;
#pragma unroll
    for (int i = 0; i < 4; i++) woff += (i < wv) ? wsum[i] : 0;
    int abspos = lo + woff + (s - c);
    if (base_node + tid < N) row_ptr[base_node + tid] = abspos;
    npos[tid] = abspos;
    __syncthreads();
    for (int i = lo + tid; i < hi; i += 256) {
        int val = binned[i];
        int r = atomicAdd(&npos[val >> 17], 1);
        esrc[r] = val & 0x1FFFF;
    }
}

// ---------------- MFMA dense kernels ----------------
// Layout facts (gfx950 mfma_f32_16x16x32_bf16):
//   A frag: lane holds A[lane&15][(lane>>4)*8 + j], j=0..7 (short8v)
//   B frag: lane holds B[(lane>>4)*8 + j][lane&15]
//   D frag: lane&15 = col, row = (lane>>4)*4 + reg
// Gather-feeding outputs are stored PLANE-MAJOR [8][N][8] bf16 (plane = col>>3)
// so each XCD's gather plane (1.6 MB) fits its private 4 MiB L2.

// Yp[8][N][8](bf16) = X[n][128](f32) @ W[64][128]^T   (no bias; added in gather)
__global__ __launch_bounds__(256) void linear_mfma(const float* __restrict__ X,
                                                   const float* __restrict__ W,
                                                   unsigned short* __restrict__ Y, int N) {
    __shared__ short8v al[16 * 16];  // 16 rows x 16 slots (K=128)
    int tid = threadIdx.x, wv = tid >> 6, lane = tid & 63;
    int lr = lane & 15, lh = lane >> 4;
    short8v bw[4];
    {
        const float* wrow = W + (size_t)(wv * 16 + lr) * 128;
#pragma unroll
        for (int kk = 0; kk < 4; kk++) {
            float tmp[8];
            *(float4*)tmp = *(const float4*)(wrow + kk * 32 + lh * 8);
            *(float4*)(tmp + 4) = *(const float4*)(wrow + kk * 32 + lh * 8 + 4);
            bw[kk] = pack8(tmp);
        }
    }
    int col = wv * 16 + lr;
    unsigned short* yb = Y + (size_t)(col >> 3) * N * 8 + (col & 7);
    int r = tid >> 4, s = tid & 15;  // staging: thread -> (row, slot)
    for (int nb = blockIdx.x * 16; nb < N; nb += gridDim.x * 16) {
        const float* xg = X + (size_t)(nb + r) * 128 + s * 8;
        float tmp[8];
        *(float4*)tmp = *(const float4*)xg;
        *(float4*)(tmp + 4) = *(const float4*)(xg + 4);
        al[r * 16 + (s ^ r)] = pack8(tmp);
        __syncthreads();
        f32x4 acc = {0.f, 0.f, 0.f, 0.f};
#pragma unroll
        for (int kk = 0; kk < 4; kk++) {
            short8v a = al[lr * 16 + ((kk * 4 + lh) ^ lr)];
            acc = __builtin_amdgcn_mfma_f32_16x16x32_bf16(a, bw[kk], acc, 0, 0, 0);
        }
#pragma unroll
        for (int ri = 0; ri < 4; ri++)
            yb[(size_t)(nb + lh * 4 + ri) * 8] = f2bf(acc[ri]);
        __syncthreads();
    }
}

// H(bf16, row-major) = relu(bn(T@W^T + b))   (T bf16 row-major, K=64)
__global__ __launch_bounds__(256) void mlp1_mfma(const unsigned short* __restrict__ T,
        const float* __restrict__ W, const float* __restrict__ b,
        const float* __restrict__ g, const float* __restrict__ be,
        const float* __restrict__ m, const float* __restrict__ v,
        unsigned short* __restrict__ H, int N) {
    __shared__ short8v al[16 * 8];  // 16 rows x 8 slots (K=64)
    int tid = threadIdx.x, wv = tid >> 6, lane = tid & 63;
    int lr = lane & 15, lh = lane >> 4;
    short8v bw[2];
    {
        const float* wrow = W + (size_t)(wv * 16 + lr) * 64;
#pragma unroll
        for (int kk = 0; kk < 2; kk++) {
            float tmp[8];
            *(float4*)tmp = *(const float4*)(wrow + kk * 32 + lh * 8);
            *(float4*)(tmp + 4) = *(const float4*)(wrow + kk * 32 + lh * 8 + 4);
            bw[kk] = pack8(tmp);
        }
    }
    int col = wv * 16 + lr;
    float bias = b[col];
    float sc = g[col] * rsqrtf(v[col] + BN_EPS);
    float cc = be[col] - m[col] * sc;
    int rr = tid >> 3, ss = tid & 7;  // staging: threads 0..127
    for (int nb = blockIdx.x * 16; nb < N; nb += gridDim.x * 16) {
        if (tid < 128) {
            const short8v* tg = (const short8v*)(T + (size_t)(nb + rr) * 64);
            al[rr * 8 + (ss ^ (rr & 7))] = tg[ss];
        }
        __syncthreads();
        f32x4 acc = {0.f, 0.f, 0.f, 0.f};
#pragma unroll
        for (int kk = 0; kk < 2; kk++) {
            short8v a = al[lr * 8 + ((kk * 4 + lh) ^ (lr & 7))];
            acc = __builtin_amdgcn_mfma_f32_16x16x32_bf16(a, bw[kk], acc, 0, 0, 0);
        }
        unsigned short* hb = H + (size_t)nb * 64 + col;
#pragma unroll
        for (int ri = 0; ri < 4; ri++) {
            float o = fmaxf((acc[ri] + bias) * sc + cc, 0.f);
            hb[(size_t)(lh * 4 + ri) * 64] = f2bf(o);
        }
        __syncthreads();
    }
}

// Yp[8][N][8](bf16) = relu(bn(T@W1^T + b1)) @ W2^T   (T bf16 row-major, K=64)
__global__ __launch_bounds__(256) void mlp2_mfma(const unsigned short* __restrict__ T,
        const float* __restrict__ W1, const float* __restrict__ b1,
        const float* __restrict__ g, const float* __restrict__ be,
        const float* __restrict__ m, const float* __restrict__ v,
        const float* __restrict__ W2, unsigned short* __restrict__ Y, int N) {
    __shared__ short8v al[16 * 8];
    __shared__ short8v hl[16 * 8];
    int tid = threadIdx.x, wv = tid >> 6, lane = tid & 63;
    int lr = lane & 15, lh = lane >> 4;
    short8v bw1[2], bw2[2];
    {
        const float* w1r = W1 + (size_t)(wv * 16 + lr) * 64;
        const float* w2r = W2 + (size_t)(wv * 16 + lr) * 64;
#pragma unroll
        for (int kk = 0; kk < 2; kk++) {
            float tmp[8];
            *(float4*)tmp = *(const float4*)(w1r + kk * 32 + lh * 8);
            *(float4*)(tmp + 4) = *(const float4*)(w1r + kk * 32 + lh * 8 + 4);
            bw1[kk] = pack8(tmp);
            *(float4*)tmp = *(const float4*)(w2r + kk * 32 + lh * 8);
            *(float4*)(tmp + 4) = *(const float4*)(w2r + kk * 32 + lh * 8 + 4);
            bw2[kk] = pack8(tmp);
        }
    }
    int col = wv * 16 + lr;
    float bias = b1[col];
    float sc = g[col] * rsqrtf(v[col] + BN_EPS);
    float cc = be[col] - m[col] * sc;
    unsigned short* hu = (unsigned short*)hl;
    unsigned short* yb = Y + (size_t)(col >> 3) * N * 8 + (col & 7);
    int rr = tid >> 3, ss = tid & 7;
    for (int nb = blockIdx.x * 16; nb < N; nb += gridDim.x * 16) {
        if (tid < 128) {
            const short8v* tg = (const short8v*)(T + (size_t)(nb + rr) * 64);
            al[rr * 8 + (ss ^ (rr & 7))] = tg[ss];
        }
        __syncthreads();
        f32x4 acc = {0.f, 0.f, 0.f, 0.f};
#pragma unroll
        for (int kk = 0; kk < 2; kk++) {
            short8v a = al[lr * 8 + ((kk * 4 + lh) ^ (lr & 7))];
            acc = __builtin_amdgcn_mfma_f32_16x16x32_bf16(a, bw1[kk], acc, 0, 0, 0);
        }
        // relu(bn(.)) -> hl (swizzled [16][64] bf16)
#pragma unroll
        for (int ri = 0; ri < 4; ri++) {
            float o = fmaxf((acc[ri] + bias) * sc + cc, 0.f);
            int row = lh * 4 + ri;
            int slot = (col >> 3) ^ (row & 7);
            hu[(row * 8 + slot) * 8 + (col & 7)] = f2bf(o);
        }
        __syncthreads();
        f32x4 acc2 = {0.f, 0.f, 0.f, 0.f};
#pragma unroll
        for (int kk = 0; kk < 2; kk++) {
            short8v a = hl[lr * 8 + ((kk * 4 + lh) ^ (lr & 7))];
            acc2 = __builtin_amdgcn_mfma_f32_16x16x32_bf16(a, bw2[kk], acc2, 0, 0, 0);
        }
#pragma unroll
        for (int ri = 0; ri < 4; ri++)
            yb[(size_t)(nb + lh * 4 + ri) * 8] = f2bf(acc2[ri]);
        __syncthreads();
    }
}

// ---------------- gather (plane-split v3: batched parallel loads) ----------------
// Yp plane-major [8][N][8] bf16: one uint4 load = full 8-feat row.
// Wave = 8 nodes x 8 edge slots. Each lane issues 4 clamped esrc loads + 4 Y loads
// covering edge slots {slot, slot+8, slot+16, slot+24} => deg<=32 with ZERO loop
// iterations and all loads independent (one esrc->Y chain of exposed latency).
// Masked words are cndmask'd to 0 (bf16 0x0000 == +0.0). Rare deg>32 remainder loop.
__global__ __launch_bounds__(256) void gather_plane(const unsigned short* __restrict__ Yp,
        const int* __restrict__ row_ptr, const int* __restrict__ esrc,
        const float* __restrict__ bias, unsigned short* __restrict__ T, int N) {
    int b = blockIdx.x;
    int p = b & 7;
    int g = b >> 3;
    int wv = threadIdx.x >> 6, lane = threadIdx.x & 63;
    int nsub = lane >> 3, slot = lane & 7;
    int node = g * 32 + wv * 8 + nsub;
    bool valid = node < N;
    int nd = valid ? node : 0;
    int e0 = row_ptr[nd];
    int e1 = valid ? row_ptr[nd + 1] : e0;
    int la = max(e1 - 1, 0);
    const uint4* Yrow = (const uint4*)(Yp + (size_t)p * N * 8);
    // batched: 4 parallel esrc loads, then 4 parallel row loads
    int eb0 = e0 + slot, eb1 = eb0 + 8, eb2 = eb0 + 16, eb3 = eb0 + 24;
    int s0 = esrc[min(eb0, la)];
    int s1 = esrc[min(eb1, la)];
    int s2 = esrc[min(eb2, la)];
    int s3 = esrc[min(eb3, la)];
    uint4 q0 = Yrow[s0];
    uint4 q1 = Yrow[s1];
    uint4 q2 = Yrow[s2];
    uint4 q3 = Yrow[s3];
    // mask invalid slots to bf16-zero (4 cndmask per row)
    bool k0 = eb0 < e1, k1 = eb1 < e1, k2 = eb2 < e1, k3 = eb3 < e1;
    q0.x = k0 ? q0.x : 0u; q0.y = k0 ? q0.y : 0u; q0.z = k0 ? q0.z : 0u; q0.w = k0 ? q0.w : 0u;
    q1.x = k1 ? q1.x : 0u; q1.y = k1 ? q1.y : 0u; q1.z = k1 ? q1.z : 0u; q1.w = k1 ? q1.w : 0u;
    q2.x = k2 ? q2.x : 0u; q2.y = k2 ? q2.y : 0u; q2.z = k2 ? q2.z : 0u; q2.w = k2 ? q2.w : 0u;
    q3.x = k3 ? q3.x : 0u; q3.y = k3 ? q3.y : 0u; q3.z = k3 ? q3.z : 0u; q3.w = k3 ? q3.w : 0u;
    float a0 = (bflo(q0.x) + bflo(q1.x)) + (bflo(q2.x) + bflo(q3.x));
    float a1 = (bfhi(q0.x) + bfhi(q1.x)) + (bfhi(q2.x) + bfhi(q3.x));
    float a2 = (bflo(q0.y) + bflo(q1.y)) + (bflo(q2.y) + bflo(q3.y));
    float a3 = (bfhi(q0.y) + bfhi(q1.y)) + (bfhi(q2.y) + bfhi(q3.y));
    float a4 = (bflo(q0.z) + bflo(q1.z)) + (bflo(q2.z) + bflo(q3.z));
    float a5 = (bfhi(q0.z) + bfhi(q1.z)) + (bfhi(q2.z) + bfhi(q3.z));
    float a6 = (bflo(q0.w) + bflo(q1.w)) + (bflo(q2.w) + bflo(q3.w));
    float a7 = (bfhi(q0.w) + bfhi(q1.w)) + (bfhi(q2.w) + bfhi(q3.w));
    // rare remainder (deg > 32)
    for (int e = e0 + 32 + slot; e < e1; e += 8) {
        int s = esrc[e];
        uint4 q = Yrow[s];
        a0 += bflo(q.x); a1 += bfhi(q.x);
        a2 += bflo(q.y); a3 += bfhi(q.y);
        a4 += bflo(q.z); a5 += bfhi(q.z);
        a6 += bflo(q.w); a7 += bfhi(q.w);
    }
#pragma unroll
    for (int off = 1; off <= 4; off <<= 1) {
        a0 += __shfl_xor(a0, off, 64);
        a1 += __shfl_xor(a1, off, 64);
        a2 += __shfl_xor(a2, off, 64);
        a3 += __shfl_xor(a3, off, 64);
        a4 += __shfl_xor(a4, off, 64);
        a5 += __shfl_xor(a5, off, 64);
        a6 += __shfl_xor(a6, off, 64);
        a7 += __shfl_xor(a7, off, 64);
    }
    if (slot == 0 && valid) {
        uint4 qs = Yrow[node];
        float4 bl = *(const float4*)(bias + p * 8);
        float4 bh = *(const float4*)(bias + p * 8 + 4);
        a0 += bflo(qs.x) + bl.x; a1 += bfhi(qs.x) + bl.y;
        a2 += bflo(qs.y) + bl.z; a3 += bfhi(qs.y) + bl.w;
        a4 += bflo(qs.z) + bh.x; a5 += bfhi(qs.z) + bh.y;
        a6 += bflo(qs.w) + bh.z; a7 += bfhi(qs.w) + bh.w;
        uint4 o;
        o.x = (unsigned int)f2bf(fmaxf(a0, 0.f)) | ((unsigned int)f2bf(fmaxf(a1, 0.f)) << 16);
        o.y = (unsigned int)f2bf(fmaxf(a2, 0.f)) | ((unsigned int)f2bf(fmaxf(a3, 0.f)) << 16);
        o.z = (unsigned int)f2bf(fmaxf(a4, 0.f)) | ((unsigned int)f2bf(fmaxf(a5, 0.f)) << 16);
        o.w = (unsigned int)f2bf(fmaxf(a6, 0.f)) | ((unsigned int)f2bf(fmaxf(a7, 0.f)) << 16);
        *(uint4*)(T + (size_t)node * 64 + p * 8) = o;
    }
}

// ---------------- mean pool per graph (batch is sorted) ----------------
__global__ __launch_bounds__(256) void pool_kernel(const unsigned short* __restrict__ H,
                                                   const int* __restrict__ batch,
                                                   float* __restrict__ out, int N) {
    __shared__ float part[4][64];
    int g = blockIdx.x;
    int tid = threadIdx.x, wv = tid >> 6, lane = tid & 63;
    int lo = 0, hi = N;
    while (lo < hi) { int mid = (lo + hi) >> 1; if (batch[mid] < g) lo = mid + 1; else hi = mid; }
    int start = lo;
    hi = N;
    while (lo < hi) { int mid = (lo + hi) >> 1; if (batch[mid] < g + 1) lo = mid + 1; else hi = mid; }
    int end = lo;
    float acc = 0.f;
    for (int i = start + wv; i < end; i += 4) acc += bf2f(H[(size_t)i * 64 + lane]);
    part[wv][lane] = acc;
    __syncthreads();
    if (tid < 64) {
        float sfin = part[0][tid] + part[1][tid] + part[2][tid] + part[3][tid];
        float cnt = (float)(end - start);
        out[(size_t)g * 64 + tid] = sfin / fmaxf(cnt, 1.f);
    }
}

extern "C" void kernel_launch(void* const* d_in, const int* in_sizes, int n_in,
                              void* d_out, int out_size, void* d_ws, size_t ws_size,
                              hipStream_t stream) {
    const float* x   = (const float*)d_in[0];
    const int*   ei  = (const int*)d_in[1];
    const int*   bat = (const int*)d_in[2];
    const float* W1a = (const float*)d_in[3];
    const float* b1a = (const float*)d_in[4];
    const float* W1b = (const float*)d_in[5];
    const float* b1b = (const float*)d_in[6];
    const float* g1  = (const float*)d_in[7];
    const float* be1 = (const float*)d_in[8];
    const float* m1  = (const float*)d_in[9];
    const float* v1  = (const float*)d_in[10];
    const float* W2a = (const float*)d_in[11];
    const float* b2a = (const float*)d_in[12];
    const float* W2b = (const float*)d_in[13];
    const float* b2b = (const float*)d_in[14];
    const float* g2  = (const float*)d_in[15];
    const float* be2 = (const float*)d_in[16];
    const float* m2  = (const float*)d_in[17];
    const float* v2  = (const float*)d_in[18];
    float* out = (float*)d_out;

    int N = in_sizes[0] / 128;
    int E = in_sizes[1] / 2;
    int G = out_size / 64;
    int nbuck = (N + 255) >> 8;

    // workspace layout (bf16 feature buffers)
    char* ws = (char*)d_ws;
    int* row_ptr = (int*)ws;                              // N+1 (padded)
    int* bcnt = row_ptr + ((N + 1 + 3) & ~3);             // MAXB
    int* boff = bcnt + MAXB;                              // MAXB+1
    int* bpos = boff + MAXB + 4;                          // MAXB
    int* esrc = bpos + MAXB;                              // E
    unsigned short* bufA = (unsigned short*)(esrc + E);   // N*64 bf16 (16B aligned)
    unsigned short* bufB = bufA + (size_t)N * 64;         // N*64 bf16
    int* binned = (int*)bufB;                             // aliases bufB (dead until gather#1)

    // CSR build
    hipMemsetAsync(bcnt, 0, MAXB * sizeof(int), stream);
    bin_count<<<512, 256, 0, stream>>>(ei, E, bcnt, nbuck);
    scan_small<<<1, 512, 0, stream>>>(bcnt, boff, bpos, row_ptr + N, nbuck, E);
    bin_scatter<<<(E + CHUNK - 1) / CHUNK, 256, 0, stream>>>(ei, E, bpos, binned, nbuck);
    bucket_csr<<<nbuck, 256, 0, stream>>>(binned, boff, row_ptr, esrc, N);

    int ngb = (N + 31) / 32;

    // layer 1
    linear_mfma<<<2048, 256, 0, stream>>>(x, W1a, bufA, N);
    gather_plane<<<8 * ngb, 256, 0, stream>>>(bufA, row_ptr, esrc, b1a, bufB, N);
    mlp2_mfma<<<2048, 256, 0, stream>>>(bufB, W1b, b1b, g1, be1, m1, v1, W2a, bufA, N);

    // layer 2
    gather_plane<<<8 * ngb, 256, 0, stream>>>(bufA, row_ptr, esrc, b2a, bufB, N);
    mlp1_mfma<<<2048, 256, 0, stream>>>(bufB, W2b, b2b, g2, be2, m2, v2, bufA, N);

    // mean pool
    pool_kernel<<<G, 256, 0, stream>>>(bufA, bat, out, N);
}

// Round 8
// 347.389 us; speedup vs baseline: 1.2308x; 1.0741x over previous
//
#include <hip/hip_runtime.h>

#define BN_EPS 1e-5f
#define CHUNK 4096
#define MAXB 512  // max buckets (N up to 131072 with 256 nodes/bucket)

typedef __attribute__((ext_vector_type(8))) short short8v;  // 8 bf16 = 4 VGPRs
typedef __attribute__((ext_vector_type(4))) float f32x4;

// bf16 helpers (RNE pack, cheap unpack)
__device__ __forceinline__ unsigned short f2bf(float f) {
    unsigned int u = __float_as_uint(f);
    u += 0x7FFF + ((u >> 16) & 1);
    return (unsigned short)(u >> 16);
}
__device__ __forceinline__ float bf2f(unsigned short h) {
    return __uint_as_float((unsigned int)h << 16);
}
__device__ __forceinline__ float bflo(unsigned int u) { return __uint_as_float(u << 16); }
__device__ __forceinline__ float bfhi(unsigned int u) { return __uint_as_float(u & 0xffff0000u); }

__device__ __forceinline__ short8v pack8(const float* f) {
    short8v r;
#pragma unroll
    for (int i = 0; i < 8; i++) r[i] = (short)f2bf(f[i]);
    return r;
}

// ---------------- CSR build: bucketed, no global random scatter ----------------

__global__ __launch_bounds__(256) void bin_count(const int* __restrict__ ei, int E,
                                                 int* __restrict__ bcnt, int nbuck) {
    __shared__ int h[MAXB];
    for (int i = threadIdx.x; i < nbuck; i += 256) h[i] = 0;
    __syncthreads();
    int i = blockIdx.x * 256 + threadIdx.x, stride = gridDim.x * 256;
    for (int e = i; e < E; e += stride) {
        int d = ei[E + e];
        atomicAdd(&h[d >> 8], 1);
    }
    __syncthreads();
    for (int b = threadIdx.x; b < nbuck; b += 256)
        if (h[b]) atomicAdd(&bcnt[b], h[b]);
}

__global__ __launch_bounds__(512) void scan_small(const int* __restrict__ bcnt,
                                                  int* __restrict__ boff,
                                                  int* __restrict__ bpos,
                                                  int* __restrict__ row_ptr_end,
                                                  int nbuck, int E) {
    __shared__ int wsum[8];
    int tid = threadIdx.x, lane = tid & 63, wv = tid >> 6;
    int val = (tid < nbuck) ? bcnt[tid] : 0;
    int s = val;
#pragma unroll
    for (int off = 1; off < 64; off <<= 1) {
        int t = __shfl_up(s, off, 64);
        if (lane >= off) s += t;
    }
    if (lane == 63) wsum[wv] = s;
    __syncthreads();
    if (wv == 0) {
        int t = (lane < 8) ? wsum[lane] : 0;
#pragma unroll
        for (int off = 1; off < 8; off <<= 1) {
            int u = __shfl_up(t, off, 64);
            if (lane >= off) t += u;
        }
        if (lane < 8) wsum[lane] = t;
    }
    __syncthreads();
    int excl = ((wv == 0) ? 0 : wsum[wv - 1]) + s - val;
    if (tid < nbuck) { boff[tid] = excl; bpos[tid] = excl; }
    if (tid == 0) { boff[nbuck] = E; *row_ptr_end = E; }
}

__global__ __launch_bounds__(256) void bin_scatter(const int* __restrict__ ei, int E,
                                                   int* __restrict__ bpos,
                                                   int* __restrict__ binned, int nbuck) {
    __shared__ int h[MAXB];
    __shared__ int res[MAXB];
    int base = blockIdx.x * CHUNK;
    int cnt = min(CHUNK, E - base);
    int tid = threadIdx.x;
    for (int b = tid; b < nbuck; b += 256) h[b] = 0;
    __syncthreads();
    for (int k = tid; k < cnt; k += 256) {
        int d = ei[E + base + k];
        atomicAdd(&h[d >> 8], 1);
    }
    __syncthreads();
    for (int b = tid; b < nbuck; b += 256) {
        int c = h[b];
        res[b] = c ? atomicAdd(&bpos[b], c) : 0;
        h[b] = 0;  // reuse as rank counter
    }
    __syncthreads();
    for (int k = tid; k < cnt; k += 256) {
        int srcv = ei[base + k];
        int d = ei[E + base + k];
        int b = d >> 8;
        int r = atomicAdd(&h[b], 1);
        binned[res[b] + r] = ((d & 255) << 17) | srcv;  // src < 2^17
    }
}

__global__ __launch_bounds__(256) void bucket_csr(const int* __restrict__ binned,
                                                  const int* __restrict__ boff,
                                                  int* __restrict__ row_ptr,
                                                  int* __restrict__ esrc, int N) {
    __shared__ int ncnt[256];
    __shared__ int npos[256];
    __shared__ int wsum[4];
    int b = blockIdx.x, tid = threadIdx.x, lane = tid & 63, wv = tid >> 6;
    int lo = boff[b], hi = boff[b + 1];
    int base_node = b << 8;
    ncnt[tid] = 0;
    __syncthreads();
    for (int i = lo + tid; i < hi; i += 256)
        atomicAdd(&ncnt[binned[i] >> 17], 1);
    __syncthreads();
    int c = ncnt[tid];
    int s = c;
#pragma unroll
    for (int off = 1; off < 64; off <<= 1) {
        int t = __shfl_up(s, off, 64);
        if (lane >= off) s += t;
    }
    if (lane == 63) wsum[wv] = s;
    __syncthreads();
    int woff = 0;
#pragma unroll
    for (int i = 0; i < 4; i++) woff += (i < wv) ? wsum[i] : 0;
    int abspos = lo + woff + (s - c);
    if (base_node + tid < N) row_ptr[base_node + tid] = abspos;
    npos[tid] = abspos;
    __syncthreads();
    for (int i = lo + tid; i < hi; i += 256) {
        int val = binned[i];
        int r = atomicAdd(&npos[val >> 17], 1);
        esrc[r] = val & 0x1FFFF;
    }
}

// ---------------- MFMA dense kernels ----------------
// Layout facts (gfx950 mfma_f32_16x16x32_bf16):
//   A frag: lane holds A[lane&15][(lane>>4)*8 + j], j=0..7 (short8v)
//   B frag: lane holds B[(lane>>4)*8 + j][lane&15]
//   D frag: lane&15 = col, row = (lane>>4)*4 + reg
// Gather-feeding outputs stored PLANE-MAJOR [4][N][16] bf16 (plane = col>>4 = wv)
// so each XCD's gather plane (3.2 MB) fits its private 4 MiB L2.

// Yp[4][N][16](bf16) = X[n][128](f32) @ W[64][128]^T   (no bias; added in gather)
__global__ __launch_bounds__(256) void linear_mfma(const float* __restrict__ X,
                                                   const float* __restrict__ W,
                                                   unsigned short* __restrict__ Y, int N) {
    __shared__ short8v al[16 * 16];  // 16 rows x 16 slots (K=128)
    int tid = threadIdx.x, wv = tid >> 6, lane = tid & 63;
    int lr = lane & 15, lh = lane >> 4;
    short8v bw[4];
    {
        const float* wrow = W + (size_t)(wv * 16 + lr) * 128;
#pragma unroll
        for (int kk = 0; kk < 4; kk++) {
            float tmp[8];
            *(float4*)tmp = *(const float4*)(wrow + kk * 32 + lh * 8);
            *(float4*)(tmp + 4) = *(const float4*)(wrow + kk * 32 + lh * 8 + 4);
            bw[kk] = pack8(tmp);
        }
    }
    // plane = (wv*16+lr)>>4 = wv; in-plane feat = lr
    unsigned short* yb = Y + (size_t)wv * N * 16 + lr;
    int r = tid >> 4, s = tid & 15;  // staging: thread -> (row, slot)
    for (int nb = blockIdx.x * 16; nb < N; nb += gridDim.x * 16) {
        const float* xg = X + (size_t)(nb + r) * 128 + s * 8;
        float tmp[8];
        *(float4*)tmp = *(const float4*)xg;
        *(float4*)(tmp + 4) = *(const float4*)(xg + 4);
        al[r * 16 + (s ^ r)] = pack8(tmp);
        __syncthreads();
        f32x4 acc = {0.f, 0.f, 0.f, 0.f};
#pragma unroll
        for (int kk = 0; kk < 4; kk++) {
            short8v a = al[lr * 16 + ((kk * 4 + lh) ^ lr)];
            acc = __builtin_amdgcn_mfma_f32_16x16x32_bf16(a, bw[kk], acc, 0, 0, 0);
        }
#pragma unroll
        for (int ri = 0; ri < 4; ri++)
            yb[(size_t)(nb + lh * 4 + ri) * 16] = f2bf(acc[ri]);
        __syncthreads();
    }
}

// H(bf16, row-major) = relu(bn(T@W^T + b))   (T bf16 row-major, K=64)
__global__ __launch_bounds__(256) void mlp1_mfma(const unsigned short* __restrict__ T,
        const float* __restrict__ W, const float* __restrict__ b,
        const float* __restrict__ g, const float* __restrict__ be,
        const float* __restrict__ m, const float* __restrict__ v,
        unsigned short* __restrict__ H, int N) {
    __shared__ short8v al[16 * 8];  // 16 rows x 8 slots (K=64)
    int tid = threadIdx.x, wv = tid >> 6, lane = tid & 63;
    int lr = lane & 15, lh = lane >> 4;
    short8v bw[2];
    {
        const float* wrow = W + (size_t)(wv * 16 + lr) * 64;
#pragma unroll
        for (int kk = 0; kk < 2; kk++) {
            float tmp[8];
            *(float4*)tmp = *(const float4*)(wrow + kk * 32 + lh * 8);
            *(float4*)(tmp + 4) = *(const float4*)(wrow + kk * 32 + lh * 8 + 4);
            bw[kk] = pack8(tmp);
        }
    }
    int col = wv * 16 + lr;
    float bias = b[col];
    float sc = g[col] * rsqrtf(v[col] + BN_EPS);
    float cc = be[col] - m[col] * sc;
    int rr = tid >> 3, ss = tid & 7;  // staging: threads 0..127
    for (int nb = blockIdx.x * 16; nb < N; nb += gridDim.x * 16) {
        if (tid < 128) {
            const short8v* tg = (const short8v*)(T + (size_t)(nb + rr) * 64);
            al[rr * 8 + (ss ^ (rr & 7))] = tg[ss];
        }
        __syncthreads();
        f32x4 acc = {0.f, 0.f, 0.f, 0.f};
#pragma unroll
        for (int kk = 0; kk < 2; kk++) {
            short8v a = al[lr * 8 + ((kk * 4 + lh) ^ (lr & 7))];
            acc = __builtin_amdgcn_mfma_f32_16x16x32_bf16(a, bw[kk], acc, 0, 0, 0);
        }
        unsigned short* hb = H + (size_t)nb * 64 + col;
#pragma unroll
        for (int ri = 0; ri < 4; ri++) {
            float o = fmaxf((acc[ri] + bias) * sc + cc, 0.f);
            hb[(size_t)(lh * 4 + ri) * 64] = f2bf(o);
        }
        __syncthreads();
    }
}

// Yp[4][N][16](bf16) = relu(bn(T@W1^T + b1)) @ W2^T   (T bf16 row-major, K=64)
__global__ __launch_bounds__(256) void mlp2_mfma(const unsigned short* __restrict__ T,
        const float* __restrict__ W1, const float* __restrict__ b1,
        const float* __restrict__ g, const float* __restrict__ be,
        const float* __restrict__ m, const float* __restrict__ v,
        const float* __restrict__ W2, unsigned short* __restrict__ Y, int N) {
    __shared__ short8v al[16 * 8];
    __shared__ short8v hl[16 * 8];
    int tid = threadIdx.x, wv = tid >> 6, lane = tid & 63;
    int lr = lane & 15, lh = lane >> 4;
    short8v bw1[2], bw2[2];
    {
        const float* w1r = W1 + (size_t)(wv * 16 + lr) * 64;
        const float* w2r = W2 + (size_t)(wv * 16 + lr) * 64;
#pragma unroll
        for (int kk = 0; kk < 2; kk++) {
            float tmp[8];
            *(float4*)tmp = *(const float4*)(w1r + kk * 32 + lh * 8);
            *(float4*)(tmp + 4) = *(const float4*)(w1r + kk * 32 + lh * 8 + 4);
            bw1[kk] = pack8(tmp);
            *(float4*)tmp = *(const float4*)(w2r + kk * 32 + lh * 8);
            *(float4*)(tmp + 4) = *(const float4*)(w2r + kk * 32 + lh * 8 + 4);
            bw2[kk] = pack8(tmp);
        }
    }
    int col = wv * 16 + lr;
    float bias = b1[col];
    float sc = g[col] * rsqrtf(v[col] + BN_EPS);
    float cc = be[col] - m[col] * sc;
    unsigned short* hu = (unsigned short*)hl;
    unsigned short* yb = Y + (size_t)wv * N * 16 + lr;
    int rr = tid >> 3, ss = tid & 7;
    for (int nb = blockIdx.x * 16; nb < N; nb += gridDim.x * 16) {
        if (tid < 128) {
            const short8v* tg = (const short8v*)(T + (size_t)(nb + rr) * 64);
            al[rr * 8 + (ss ^ (rr & 7))] = tg[ss];
        }
        __syncthreads();
        f32x4 acc = {0.f, 0.f, 0.f, 0.f};
#pragma unroll
        for (int kk = 0; kk < 2; kk++) {
            short8v a = al[lr * 8 + ((kk * 4 + lh) ^ (lr & 7))];
            acc = __builtin_amdgcn_mfma_f32_16x16x32_bf16(a, bw1[kk], acc, 0, 0, 0);
        }
        // relu(bn(.)) -> hl (swizzled [16][64] bf16)
#pragma unroll
        for (int ri = 0; ri < 4; ri++) {
            float o = fmaxf((acc[ri] + bias) * sc + cc, 0.f);
            int row = lh * 4 + ri;
            int slot = (col >> 3) ^ (row & 7);
            hu[(row * 8 + slot) * 8 + (col & 7)] = f2bf(o);
        }
        __syncthreads();
        f32x4 acc2 = {0.f, 0.f, 0.f, 0.f};
#pragma unroll
        for (int kk = 0; kk < 2; kk++) {
            short8v a = hl[lr * 8 + ((kk * 4 + lh) ^ (lr & 7))];
            acc2 = __builtin_amdgcn_mfma_f32_16x16x32_bf16(a, bw2[kk], acc2, 0, 0, 0);
        }
#pragma unroll
        for (int ri = 0; ri < 4; ri++)
            yb[(size_t)(nb + lh * 4 + ri) * 16] = f2bf(acc2[ri]);
        __syncthreads();
    }
}

// ---------------- gather (plane-split v4: 4 planes, lane-pair rows) ----------------
// Yp plane-major [4][N][16] bf16: row = 32B; 2 lanes (half=lane&1) each load 16B of the
// SAME row in the SAME instruction -> one cache-line visit per edge per plane.
// 4 planes x E = 6.4M line-visits (the L2-resident floor). Plane p -> XCD p, p+4.
// Wave = 4 nodes x (8 slots x 2 halves); 4 clamped batches cover deg<=32 load-parallel.
__global__ __launch_bounds__(256) void gather_plane(const unsigned short* __restrict__ Yp,
        const int* __restrict__ row_ptr, const int* __restrict__ esrc,
        const float* __restrict__ bias, unsigned short* __restrict__ T, int N) {
    int b = blockIdx.x;
    int p = b & 3;
    int g = b >> 2;
    int wv = threadIdx.x >> 6, lane = threadIdx.x & 63;
    int half = lane & 1, slot = (lane >> 1) & 7, nsub = lane >> 4;
    int node = g * 16 + wv * 4 + nsub;
    bool valid = node < N;
    int nd = valid ? node : 0;
    int e0 = row_ptr[nd];
    int e1 = valid ? row_ptr[nd + 1] : e0;
    int la = max(e1 - 1, 0);
    const uint4* Yh = (const uint4*)(Yp + (size_t)p * N * 16);  // index: src*2 + half
    int eb0 = e0 + slot, eb1 = eb0 + 8, eb2 = eb0 + 16, eb3 = eb0 + 24;
    int s0 = esrc[min(eb0, la)];
    int s1 = esrc[min(eb1, la)];
    int s2 = esrc[min(eb2, la)];
    int s3 = esrc[min(eb3, la)];
    uint4 q0 = Yh[s0 * 2 + half];
    uint4 q1 = Yh[s1 * 2 + half];
    uint4 q2 = Yh[s2 * 2 + half];
    uint4 q3 = Yh[s3 * 2 + half];
    bool k0 = eb0 < e1, k1 = eb1 < e1, k2 = eb2 < e1, k3 = eb3 < e1;
    q0.x = k0 ? q0.x : 0u; q0.y = k0 ? q0.y : 0u; q0.z = k0 ? q0.z : 0u; q0.w = k0 ? q0.w : 0u;
    q1.x = k1 ? q1.x : 0u; q1.y = k1 ? q1.y : 0u; q1.z = k1 ? q1.z : 0u; q1.w = k1 ? q1.w : 0u;
    q2.x = k2 ? q2.x : 0u; q2.y = k2 ? q2.y : 0u; q2.z = k2 ? q2.z : 0u; q2.w = k2 ? q2.w : 0u;
    q3.x = k3 ? q3.x : 0u; q3.y = k3 ? q3.y : 0u; q3.z = k3 ? q3.z : 0u; q3.w = k3 ? q3.w : 0u;
    float a0 = (bflo(q0.x) + bflo(q1.x)) + (bflo(q2.x) + bflo(q3.x));
    float a1 = (bfhi(q0.x) + bfhi(q1.x)) + (bfhi(q2.x) + bfhi(q3.x));
    float a2 = (bflo(q0.y) + bflo(q1.y)) + (bflo(q2.y) + bflo(q3.y));
    float a3 = (bfhi(q0.y) + bfhi(q1.y)) + (bfhi(q2.y) + bfhi(q3.y));
    float a4 = (bflo(q0.z) + bflo(q1.z)) + (bflo(q2.z) + bflo(q3.z));
    float a5 = (bfhi(q0.z) + bfhi(q1.z)) + (bfhi(q2.z) + bfhi(q3.z));
    float a6 = (bflo(q0.w) + bflo(q1.w)) + (bflo(q2.w) + bflo(q3.w));
    float a7 = (bfhi(q0.w) + bfhi(q1.w)) + (bfhi(q2.w) + bfhi(q3.w));
    // rare remainder (deg > 32)
    for (int e = e0 + 32 + slot; e < e1; e += 8) {
        int s = esrc[e];
        uint4 q = Yh[s * 2 + half];
        a0 += bflo(q.x); a1 += bfhi(q.x);
        a2 += bflo(q.y); a3 += bfhi(q.y);
        a4 += bflo(q.z); a5 += bfhi(q.z);
        a6 += bflo(q.w); a7 += bfhi(q.w);
    }
    // reduce across the 8 slots (lane bits 1..3), preserving half & nsub
#pragma unroll
    for (int off = 2; off <= 8; off <<= 1) {
        a0 += __shfl_xor(a0, off, 64);
        a1 += __shfl_xor(a1, off, 64);
        a2 += __shfl_xor(a2, off, 64);
        a3 += __shfl_xor(a3, off, 64);
        a4 += __shfl_xor(a4, off, 64);
        a5 += __shfl_xor(a5, off, 64);
        a6 += __shfl_xor(a6, off, 64);
        a7 += __shfl_xor(a7, off, 64);
    }
    if (slot == 0 && valid) {
        uint4 qs = Yh[node * 2 + half];
        const float4* bp = (const float4*)(bias + p * 16 + half * 8);
        float4 bl = bp[0];
        float4 bh = bp[1];
        a0 += bflo(qs.x) + bl.x; a1 += bfhi(qs.x) + bl.y;
        a2 += bflo(qs.y) + bl.z; a3 += bfhi(qs.y) + bl.w;
        a4 += bflo(qs.z) + bh.x; a5 += bfhi(qs.z) + bh.y;
        a6 += bflo(qs.w) + bh.z; a7 += bfhi(qs.w) + bh.w;
        uint4 o;
        o.x = (unsigned int)f2bf(fmaxf(a0, 0.f)) | ((unsigned int)f2bf(fmaxf(a1, 0.f)) << 16);
        o.y = (unsigned int)f2bf(fmaxf(a2, 0.f)) | ((unsigned int)f2bf(fmaxf(a3, 0.f)) << 16);
        o.z = (unsigned int)f2bf(fmaxf(a4, 0.f)) | ((unsigned int)f2bf(fmaxf(a5, 0.f)) << 16);
        o.w = (unsigned int)f2bf(fmaxf(a6, 0.f)) | ((unsigned int)f2bf(fmaxf(a7, 0.f)) << 16);
        *(uint4*)(T + (size_t)node * 64 + p * 16 + half * 8) = o;
    }
}

// ---------------- mean pool per graph (batch is sorted) ----------------
__global__ __launch_bounds__(256) void pool_kernel(const unsigned short* __restrict__ H,
                                                   const int* __restrict__ batch,
                                                   float* __restrict__ out, int N) {
    __shared__ float part[4][64];
    int g = blockIdx.x;
    int tid = threadIdx.x, wv = tid >> 6, lane = tid & 63;
    int lo = 0, hi = N;
    while (lo < hi) { int mid = (lo + hi) >> 1; if (batch[mid] < g) lo = mid + 1; else hi = mid; }
    int start = lo;
    hi = N;
    while (lo < hi) { int mid = (lo + hi) >> 1; if (batch[mid] < g + 1) lo = mid + 1; else hi = mid; }
    int end = lo;
    float acc = 0.f;
    for (int i = start + wv; i < end; i += 4) acc += bf2f(H[(size_t)i * 64 + lane]);
    part[wv][lane] = acc;
    __syncthreads();
    if (tid < 64) {
        float sfin = part[0][tid] + part[1][tid] + part[2][tid] + part[3][tid];
        float cnt = (float)(end - start);
        out[(size_t)g * 64 + tid] = sfin / fmaxf(cnt, 1.f);
    }
}

extern "C" void kernel_launch(void* const* d_in, const int* in_sizes, int n_in,
                              void* d_out, int out_size, void* d_ws, size_t ws_size,
                              hipStream_t stream) {
    const float* x   = (const float*)d_in[0];
    const int*   ei  = (const int*)d_in[1];
    const int*   bat = (const int*)d_in[2];
    const float* W1a = (const float*)d_in[3];
    const float* b1a = (const float*)d_in[4];
    const float* W1b = (const float*)d_in[5];
    const float* b1b = (const float*)d_in[6];
    const float* g1  = (const float*)d_in[7];
    const float* be1 = (const float*)d_in[8];
    const float* m1  = (const float*)d_in[9];
    const float* v1  = (const float*)d_in[10];
    const float* W2a = (const float*)d_in[11];
    const float* b2a = (const float*)d_in[12];
    const float* W2b = (const float*)d_in[13];
    const float* b2b = (const float*)d_in[14];
    const float* g2  = (const float*)d_in[15];
    const float* be2 = (const float*)d_in[16];
    const float* m2  = (const float*)d_in[17];
    const float* v2  = (const float*)d_in[18];
    float* out = (float*)d_out;

    int N = in_sizes[0] / 128;
    int E = in_sizes[1] / 2;
    int G = out_size / 64;
    int nbuck = (N + 255) >> 8;

    // workspace layout (bf16 feature buffers)
    char* ws = (char*)d_ws;
    int* row_ptr = (int*)ws;                              // N+1 (padded)
    int* bcnt = row_ptr + ((N + 1 + 3) & ~3);             // MAXB
    int* boff = bcnt + MAXB;                              // MAXB+1
    int* bpos = boff + MAXB + 4;                          // MAXB
    int* esrc = bpos + MAXB;                              // E
    unsigned short* bufA = (unsigned short*)(esrc + E);   // N*64 bf16 (16B aligned)
    unsigned short* bufB = bufA + (size_t)N * 64;         // N*64 bf16
    int* binned = (int*)bufB;                             // aliases bufB (dead until gather#1)

    // CSR build
    hipMemsetAsync(bcnt, 0, MAXB * sizeof(int), stream);
    bin_count<<<512, 256, 0, stream>>>(ei, E, bcnt, nbuck);
    scan_small<<<1, 512, 0, stream>>>(bcnt, boff, bpos, row_ptr + N, nbuck, E);
    bin_scatter<<<(E + CHUNK - 1) / CHUNK, 256, 0, stream>>>(ei, E, bpos, binned, nbuck);
    bucket_csr<<<nbuck, 256, 0, stream>>>(binned, boff, row_ptr, esrc, N);

    int ngb = (N + 15) / 16;

    // layer 1
    linear_mfma<<<2048, 256, 0, stream>>>(x, W1a, bufA, N);
    gather_plane<<<4 * ngb, 256, 0, stream>>>(bufA, row_ptr, esrc, b1a, bufB, N);
    mlp2_mfma<<<2048, 256, 0, stream>>>(bufB, W1b, b1b, g1, be1, m1, v1, W2a, bufA, N);

    // layer 2
    gather_plane<<<4 * ngb, 256, 0, stream>>>(bufA, row_ptr, esrc, b2a, bufB, N);
    mlp1_mfma<<<2048, 256, 0, stream>>>(bufB, W2b, b2b, g2, be2, m2, v2, bufA, N);

    // mean pool
    pool_kernel<<<G, 256, 0, stream>>>(bufA, bat, out, N);
}